// Round 2
// baseline (347.076 us; speedup 1.0000x reference)
//
#include <hip/hip_runtime.h>
#include <hip/hip_bf16.h>

#define BB 8
#define NN 2048
#define DD 128

typedef __attribute__((ext_vector_type(8))) __bf16 bf16x8;
typedef __attribute__((ext_vector_type(4))) float f32x4;
typedef __attribute__((ext_vector_type(4))) int   i32x4;

static __device__ __forceinline__ unsigned short f2bf(float f) {
    union { float f; unsigned u; } v; v.f = f;
    unsigned r = (v.u + 0x7FFFu + ((v.u >> 16) & 1u)) >> 16;
    return (unsigned short)r;
}
static __device__ __forceinline__ float bf2f(unsigned short b) {
    union { unsigned u; float f; } v; v.u = ((unsigned)b) << 16;
    return v.f;
}
static __device__ __forceinline__ i32x4 pack8(f32x4 a, f32x4 c) {
    unsigned q0 = f2bf(a.x) | ((unsigned)f2bf(a.y) << 16);
    unsigned q1 = f2bf(a.z) | ((unsigned)f2bf(a.w) << 16);
    unsigned q2 = f2bf(c.x) | ((unsigned)f2bf(c.y) << 16);
    unsigned q3 = f2bf(c.z) | ((unsigned)f2bf(c.w) << 16);
    i32x4 r = {(int)q0, (int)q1, (int)q2, (int)q3};
    return r;
}

// Device-scope grid barrier. Safe because grid=256 blocks at 1 block/CU on a
// 256-CU chip (LDS 152.3KB/160KB, VGPR capped 256 by launch_bounds) -> all
// blocks co-resident. Counter zeroed by kernP (stream-ordered before kernF).
static __device__ __forceinline__ void gridBarrier(unsigned* cnt, unsigned target) {
    __syncthreads();                       // drains each thread's vmem (vmcnt0)
    if (threadIdx.x == 0) {
        __threadfence();                   // agent-scope release (L2 writeback)
        atomicAdd(cnt, 1u);
        while (__hip_atomic_load(cnt, __ATOMIC_ACQUIRE, __HIP_MEMORY_SCOPE_AGENT) < target) {
            __builtin_amdgcn_s_sleep(2);
        }
    }
    __syncthreads();
}

// ---------------------------------------------------------------------------
// kernP (unchanged, proven): pack Ptilde[i][j] = punct[i][j] & mask_j into
// bits (64 words/row), scale[i] = mask_i ? 1/max(nbr,1) : 0, pdm[i] = masked
// diagonal. One wave per row. Also zero-inits the grid-barrier counter.
// ---------------------------------------------------------------------------
__global__ __launch_bounds__(256) void kernP(
    const int* __restrict__ punct, const int* __restrict__ mask,
    unsigned* __restrict__ pk, float* __restrict__ scale_g, float* __restrict__ pdm_g,
    unsigned* __restrict__ cnt)
{
    if (blockIdx.x == 0 && threadIdx.x == 0) *cnt = 0u;

    const int t = threadIdx.x;
    const int wave = t >> 6, lane = t & 63;
    const int row_g = blockIdx.x * 4 + wave;        // 0..16383
    const int b = row_g >> 11;
    const int i = row_g & (NN - 1);

    const int* prow = punct + (size_t)row_g * NN;
    const int* mrow = mask + (size_t)b * NN;

    unsigned pk0 = 0, pk1 = 0;
    int acc = 0;
    #pragma unroll 4
    for (int w = 0; w < 32; ++w) {
        const int col = w * 64 + lane;
        const int p = prow[col];
        const int m = mrow[col];
        const int pred = (p & m) & 1;
        unsigned long long bal = __ballot(pred);
        if (lane == w) { pk0 = (unsigned)bal; pk1 = (unsigned)(bal >> 32); }
        acc += pred + ((col == i ? pred : 0) << 16);
    }
    #pragma unroll
    for (int o = 32; o > 0; o >>= 1) acc += __shfl_xor(acc, o, 64);

    if (lane < 32) {
        uint2 w2; w2.x = pk0; w2.y = pk1;
        *(uint2*)(pk + (size_t)row_g * 64 + 2 * lane) = w2;
    }
    if (lane == 0) {
        const int nall = acc & 0xFFFF;
        const int pdm  = acc >> 16;
        const int mi   = mrow[i];
        const int nbr  = nall - pdm;
        scale_g[row_g] = mi ? 1.f / (float)(nbr < 1 ? 1 : nbr) : 0.f;
        pdm_g[row_g]   = (float)pdm;
    }
}

// ---------------------------------------------------------------------------
// kernF: the entire 2-step iteration, fused. Grid 256 x 512 thr, 1 block/CU.
// Block = (batch b = blockIdx&7, rows i0..i0+63). Per step:
//   B phase: dw=sigmoid(x.w_nw+b); si = x@Ws^T + b_self (REGISTERS);
//            yhat = dw * (x@Wp^T) (REGISTERS, bf16-rounded); yT[step] global.
//   grid barrier (yT panel complete)
//   C phase: acc = Ptilde @ yhat  (A from packed bits in LDS, B from yT in
//            L2); x = relu(si + scale*(acc - pdm*yhat_i)); step0 -> x to LDS
//            (f32 + swizzled bf16) for step1; step1 -> x_out global.
// si/yhat never touch global memory; weights converted once into swizzled
// LDS (2-way-free ds_read_b128); identical rounding chain to the 286us kernel.
// ---------------------------------------------------------------------------
#define SMEM_BYTES 152320

__global__ __launch_bounds__(512) void kernF(
    const float* __restrict__ node,
    const float* __restrict__ w_nw, const float* __restrict__ b_nw,
    const float* __restrict__ w_self, const float* __restrict__ b_self,
    const float* __restrict__ w_punct,
    const unsigned* __restrict__ pk,
    const float* __restrict__ scale_g, const float* __restrict__ pdm_g,
    unsigned short* __restrict__ yT0, unsigned short* __restrict__ yT1,
    float* __restrict__ x_out, float* __restrict__ aw,
    unsigned* __restrict__ cnt)
{
    extern __shared__ char smem[];
    unsigned short* wsL   = (unsigned short*)(smem);            // [e][k] bf16, XOR-swz
    unsigned short* wpL   = (unsigned short*)(smem + 32768);    // [e][k] bf16, XOR-swz
    unsigned*       pPk   = (unsigned*)(smem + 65536);          // [64][68]
    unsigned short* ytl   = (unsigned short*)(smem + 82944);    // [128][72]
    float*          xLf   = (float*)(smem + 101376);            // [64][128] f32
    unsigned short* xLb   = (unsigned short*)(smem + 134144);   // [64][128] bf16, XOR-swz
    float*          dw_l  = (float*)(smem + 150528);            // [64]
    float*          wnw_l = (float*)(smem + 150784);            // [128]
    float*          bself_l = (float*)(smem + 151296);          // [128]
    float*          scl_l = (float*)(smem + 151808);            // [64]
    float*          pdm_l = (float*)(smem + 152064);            // [64]

    const int t  = threadIdx.x;
    const int b  = blockIdx.x & 7;              // batch -> XCD locality
    const int i0 = (blockIdx.x >> 3) * 64;
    const size_t rg0 = (size_t)b * NN + i0;

    // ---- prologue: weights f32->bf16 into XOR-swizzled LDS ----
    {
        const int e = t >> 2, k0 = (t & 3) * 32;
        const float* s1 = w_self  + (size_t)e * DD + k0;
        const float* s2 = w_punct + (size_t)e * DD + k0;
        #pragma unroll
        for (int c = 0; c < 4; ++c) {
            const int off = (e << 8) + (((k0 * 2) + (c << 4)) ^ ((e & 7) << 4));
            f32x4 a = *(const f32x4*)(s1 + c * 8);
            f32x4 d = *(const f32x4*)(s1 + c * 8 + 4);
            *(i32x4*)((char*)wsL + off) = pack8(a, d);
            f32x4 a2 = *(const f32x4*)(s2 + c * 8);
            f32x4 d2 = *(const f32x4*)(s2 + c * 8 + 4);
            *(i32x4*)((char*)wpL + off) = pack8(a2, d2);
        }
    }
    // packed-bit rows for this block (persistent across both C phases)
    #pragma unroll
    for (int r = 0; r < 2; ++r) {
        const int u = r * 512 + t;
        const int row = u >> 4, wq = (u & 15) * 4;
        i32x4 v = *(const i32x4*)(pk + (rg0 + row) * 64 + wq);
        *(i32x4*)&pPk[row * 68 + wq] = v;
    }
    if (t < 64)  { scl_l[t] = scale_g[rg0 + t]; pdm_l[t] = pdm_g[rg0 + t]; }
    if (t < 128) { wnw_l[t] = w_nw[t]; bself_l[t] = b_self[t]; }
    __syncthreads();

    const int wave = t >> 6, lane = t & 63;
    const int wm = wave >> 2, wn = wave & 3;     // row-half / e-quarter
    const int quad = lane >> 4, l16 = lane & 15;
    const float bnw0 = b_nw[0];

    f32x4 accs[2][2];   // si, carried B->C in registers
    f32x4 yv[2][2];     // bf16-rounded yhat, carried B->C in registers

    for (int step = 0; step < 2; ++step) {
        unsigned short* yTs = step ? yT1 : yT0;

        // ---- dw = sigmoid(x . w_nw + b_nw), one row per 8-lane group ----
        {
            const int drow = wave * 8 + (lane >> 3);
            const int dseg = (lane & 7) * 16;
            const float* xr = step ? (xLf + drow * DD + dseg)
                                   : (node + (rg0 + drow) * DD + dseg);
            f32x4 a0 = *(const f32x4*)xr,        a1 = *(const f32x4*)(xr + 4);
            f32x4 a2 = *(const f32x4*)(xr + 8),  a3 = *(const f32x4*)(xr + 12);
            const float* wr = wnw_l + dseg;
            float s = a0.x*wr[0]  + a0.y*wr[1]  + a0.z*wr[2]  + a0.w*wr[3]
                    + a1.x*wr[4]  + a1.y*wr[5]  + a1.z*wr[6]  + a1.w*wr[7]
                    + a2.x*wr[8]  + a2.y*wr[9]  + a2.z*wr[10] + a2.w*wr[11]
                    + a3.x*wr[12] + a3.y*wr[13] + a3.z*wr[14] + a3.w*wr[15];
            s += __shfl_xor(s, 1, 64);
            s += __shfl_xor(s, 2, 64);
            s += __shfl_xor(s, 4, 64);
            if ((lane & 7) == 0) {
                float dv = 1.f / (1.f + __expf(-(s + bnw0)));
                dw_l[drow] = dv;
                aw[((size_t)b * 2 + step) * NN + i0 + drow] = dv;
            }
        }

        // ---- GEMMs: si = x@Ws^T, infop = x@Wp^T (64 rows x 128 e) ----
        f32x4 accp[2][2];
        #pragma unroll
        for (int mt = 0; mt < 2; ++mt)
            #pragma unroll
            for (int nt = 0; nt < 2; ++nt) {
                accs[mt][nt] = (f32x4){0.f, 0.f, 0.f, 0.f};
                accp[mt][nt] = (f32x4){0.f, 0.f, 0.f, 0.f};
            }
        #pragma unroll
        for (int kk = 0; kk < 4; ++kk) {
            const int k0 = kk * 32 + quad * 8;
            bf16x8 af[2], bs[2], bp[2];
            #pragma unroll
            for (int mt = 0; mt < 2; ++mt) {
                const int rl = wm * 32 + mt * 16 + l16;
                if (step == 0) {
                    const float* xs = node + (rg0 + rl) * DD + k0;
                    f32x4 a = *(const f32x4*)xs, c = *(const f32x4*)(xs + 4);
                    union { i32x4 i; bf16x8 h; } cv; cv.i = pack8(a, c);
                    af[mt] = cv.h;
                } else {
                    const int off = (rl << 8) + ((k0 * 2) ^ ((rl & 7) << 4));
                    af[mt] = *(const bf16x8*)((char*)xLb + off);
                }
            }
            #pragma unroll
            for (int nt = 0; nt < 2; ++nt) {
                const int e = wn * 32 + nt * 16 + l16;
                const int off = (e << 8) + ((k0 * 2) ^ ((e & 7) << 4));
                bs[nt] = *(const bf16x8*)((char*)wsL + off);
                bp[nt] = *(const bf16x8*)((char*)wpL + off);
            }
            #pragma unroll
            for (int mt = 0; mt < 2; ++mt)
                #pragma unroll
                for (int nt = 0; nt < 2; ++nt) {
                    accs[mt][nt] = __builtin_amdgcn_mfma_f32_16x16x32_bf16(af[mt], bs[nt], accs[mt][nt], 0, 0, 0);
                    accp[mt][nt] = __builtin_amdgcn_mfma_f32_16x16x32_bf16(af[mt], bp[nt], accp[mt][nt], 0, 0, 0);
                }
        }
        __syncthreads();   // dw_l ready

        // ---- B epilogue: si += bias; yhat = dw*infop (rounded); ytl ----
        #pragma unroll
        for (int mt = 0; mt < 2; ++mt)
            #pragma unroll
            for (int nt = 0; nt < 2; ++nt) {
                const int e = wn * 32 + nt * 16 + l16;
                const float bsv = bself_l[e];
                #pragma unroll
                for (int r = 0; r < 4; ++r) {
                    const int rl = wm * 32 + mt * 16 + quad * 4 + r;
                    accs[mt][nt][r] += bsv;
                    const float yval = dw_l[rl] * accp[mt][nt][r];
                    const unsigned short ub = f2bf(yval);
                    yv[mt][nt][r] = bf2f(ub);
                    ytl[e * 72 + rl] = ub;
                }
            }
        __syncthreads();
        {   // coalesced yT[step] write: [b][e][n]
            const int e2 = t >> 2, qh = t & 3;
            const i32x4* src = (const i32x4*)&ytl[e2 * 72 + qh * 16];
            i32x4 v0 = src[0], v1 = src[1];
            i32x4* dst = (i32x4*)(yTs + (size_t)(b * DD + e2) * NN + i0 + qh * 16);
            dst[0] = v0; dst[1] = v1;
        }

        gridBarrier(cnt, 256u * (unsigned)(step + 1));

        // ---- C phase: acc = Ptilde @ yhat ----
        f32x4 acc[2][2];
        #pragma unroll
        for (int mt = 0; mt < 2; ++mt)
            #pragma unroll
            for (int nt = 0; nt < 2; ++nt)
                acc[mt][nt] = (f32x4){0.f, 0.f, 0.f, 0.f};

        const unsigned short* yTb = yTs + (size_t)b * DD * NN;
        #pragma unroll 4
        for (int kk = 0; kk < 64; ++kk) {
            bf16x8 bfr[2];
            #pragma unroll
            for (int nt = 0; nt < 2; ++nt) {
                const int e = wn * 32 + nt * 16 + l16;
                bfr[nt] = *(const bf16x8*)(yTb + (size_t)e * NN + kk * 32 + quad * 8);
            }
            bf16x8 af[2];
            #pragma unroll
            for (int mt = 0; mt < 2; ++mt) {
                const unsigned w = pPk[(wm * 32 + mt * 16 + l16) * 68 + kk];
                const unsigned by = (w >> (quad * 8)) & 0xFFu;
                i32x4 ex;
                ex.x = ((by &   1u) ? 0x3F80 : 0) | ((by &   2u) ? 0x3F800000 : 0);
                ex.y = ((by &   4u) ? 0x3F80 : 0) | ((by &   8u) ? 0x3F800000 : 0);
                ex.z = ((by &  16u) ? 0x3F80 : 0) | ((by &  32u) ? 0x3F800000 : 0);
                ex.w = ((by &  64u) ? 0x3F80 : 0) | ((by & 128u) ? 0x3F800000 : 0);
                union { i32x4 i; bf16x8 h; } cv; cv.i = ex;
                af[mt] = cv.h;
            }
            #pragma unroll
            for (int mt = 0; mt < 2; ++mt)
                #pragma unroll
                for (int nt = 0; nt < 2; ++nt)
                    acc[mt][nt] = __builtin_amdgcn_mfma_f32_16x16x32_bf16(af[mt], bfr[nt], acc[mt][nt], 0, 0, 0);
        }

        // ---- C epilogue: x = relu(si + scale*(acc - pdm*yhat_i)) ----
        #pragma unroll
        for (int mt = 0; mt < 2; ++mt)
            #pragma unroll
            for (int nt = 0; nt < 2; ++nt) {
                const int e = wn * 32 + nt * 16 + l16;
                #pragma unroll
                for (int r = 0; r < 4; ++r) {
                    const int rl = wm * 32 + mt * 16 + quad * 4 + r;
                    float v = accs[mt][nt][r] + scl_l[rl] * (acc[mt][nt][r] - pdm_l[rl] * yv[mt][nt][r]);
                    v = fmaxf(v, 0.f);
                    if (step == 0) {
                        xLf[rl * DD + e] = v;
                        const int off = (rl << 8) + ((e * 2) ^ ((rl & 7) << 4));
                        *(unsigned short*)((char*)xLb + off) = f2bf(v);
                    } else {
                        x_out[(rg0 + rl) * DD + e] = v;
                    }
                }
            }
        if (step == 0) __syncthreads();   // xLf/xLb ready for step-1 B phase
    }
}

extern "C" void kernel_launch(void* const* d_in, const int* in_sizes, int n_in,
                              void* d_out, int out_size, void* d_ws, size_t ws_size,
                              hipStream_t stream) {
    const float* node   = (const float*)d_in[0];
    const int*   mask   = (const int*)  d_in[1];
    const int*   punct  = (const int*)  d_in[2];
    const float* w_nw   = (const float*)d_in[3];
    const float* b_nw   = (const float*)d_in[4];
    const float* w_self = (const float*)d_in[5];
    const float* b_self = (const float*)d_in[6];
    const float* w_punct= (const float*)d_in[7];

    float* xout = (float*)d_out;
    float* aw   = xout + (size_t)BB * NN * DD;

    char* w = (char*)d_ws;
    unsigned short* yT0 = (unsigned short*)w;                            // 4 MB
    unsigned short* yT1 = (unsigned short*)(w + (4u << 20));             // 4 MB
    unsigned*       pk  = (unsigned*)(w + (8u << 20));                   // 4 MB
    float*          scl = (float*)(w + (12u << 20));                     // 64 KB
    float*          pdm = (float*)(w + (12u << 20) + (64u << 10));       // 64 KB
    unsigned*       cnt = (unsigned*)(w + (12u << 20) + (128u << 10));   // 4 B

    static bool attrSet = false;
    if (!attrSet) {
        hipFuncSetAttribute(reinterpret_cast<const void*>(kernF),
                            hipFuncAttributeMaxDynamicSharedMemorySize, SMEM_BYTES);
        attrSet = true;
    }

    kernP<<<dim3(4096), dim3(256), 0, stream>>>(punct, mask, pk, scl, pdm, cnt);
    kernF<<<dim3(256), dim3(512), SMEM_BYTES, stream>>>(
        node, w_nw, b_nw, w_self, b_self, w_punct,
        pk, scl, pdm, yT0, yT1, xout, aw, cnt);
}

// Round 3
// 319.777 us; speedup vs baseline: 1.0854x; 1.0854x over previous
//
#include <hip/hip_runtime.h>
#include <hip/hip_bf16.h>

#define BB 8
#define NN 2048
#define DD 128

typedef __attribute__((ext_vector_type(8))) __bf16 bf16x8;
typedef __attribute__((ext_vector_type(4))) float f32x4;
typedef __attribute__((ext_vector_type(4))) int   i32x4;

static __device__ __forceinline__ unsigned short f2bf(float f) {
    union { float f; unsigned u; } v; v.f = f;
    unsigned r = (v.u + 0x7FFFu + ((v.u >> 16) & 1u)) >> 16;
    return (unsigned short)r;
}
static __device__ __forceinline__ float bf2f(unsigned short b) {
    union { unsigned u; float f; } v; v.u = ((unsigned)b) << 16;
    return v.f;
}
static __device__ __forceinline__ i32x4 pack8(f32x4 a, f32x4 c) {
    unsigned q0 = f2bf(a.x) | ((unsigned)f2bf(a.y) << 16);
    unsigned q1 = f2bf(a.z) | ((unsigned)f2bf(a.w) << 16);
    unsigned q2 = f2bf(c.x) | ((unsigned)f2bf(c.y) << 16);
    unsigned q3 = f2bf(c.z) | ((unsigned)f2bf(c.w) << 16);
    i32x4 r = {(int)q0, (int)q1, (int)q2, (int)q3};
    return r;
}

// ---------------------------------------------------------------------------
// kernF: entire pipeline in ONE kernel. Grid 256 x 512 thr, 1 block/CU
// (LDS 152.6KB), all blocks co-resident -> manual grid barrier is safe.
//
// Barrier protocol (round-3 fix): arrival = release fetch_add (one wbl2);
// spin = RELAXED loads (no per-poll cache invalidate — round 2's acquire-
// in-loop invalidated the XCD L2 continuously and cost ~120us of stall);
// exit = ONE acquire load, then s_barrier. Canonical grid.sync() pattern.
//
// Ptilde packing (ex-kernP) is fused: each block packs its own 64 rows from
// punct directly into LDS pPk between barrier ARRIVAL and barrier WAIT, so
// the ~22us BW-bound pack hides the arrival spread.
// ---------------------------------------------------------------------------
#define SMEM_BYTES 152576

__global__ __launch_bounds__(512) void kernF(
    const float* __restrict__ node,
    const int* __restrict__ mask, const int* __restrict__ punct,
    const float* __restrict__ w_nw, const float* __restrict__ b_nw,
    const float* __restrict__ w_self, const float* __restrict__ b_self,
    const float* __restrict__ w_punct,
    unsigned short* __restrict__ yT0, unsigned short* __restrict__ yT1,
    float* __restrict__ x_out, float* __restrict__ aw,
    unsigned* __restrict__ cnt)
{
    extern __shared__ char smem[];
    unsigned short* wsL   = (unsigned short*)(smem);            // [e][k] bf16, XOR-swz
    unsigned short* wpL   = (unsigned short*)(smem + 32768);    // [e][k] bf16, XOR-swz
    unsigned*       pPk   = (unsigned*)(smem + 65536);          // [64][68]
    unsigned short* ytl   = (unsigned short*)(smem + 82944);    // [128][72]
    float*          xLf   = (float*)(smem + 101376);            // [64][128] f32
    unsigned short* xLb   = (unsigned short*)(smem + 134144);   // [64][128] bf16, XOR-swz
    float*          dw_l  = (float*)(smem + 150528);            // [64]
    float*          wnw_l = (float*)(smem + 150784);            // [128]
    float*          bself_l = (float*)(smem + 151296);          // [128]
    float*          scl_l = (float*)(smem + 151808);            // [64]
    float*          pdm_l = (float*)(smem + 152064);            // [64]
    int*            nbr_l = (int*)(smem + 152320);              // [64]

    const int t  = threadIdx.x;
    const int b  = blockIdx.x & 7;              // batch -> XCD locality
    const int i0 = (blockIdx.x >> 3) * 64;
    const size_t rg0 = (size_t)b * NN + i0;

    // ---- prologue: weights f32->bf16 into XOR-swizzled LDS ----
    {
        const int e = t >> 2, k0 = (t & 3) * 32;
        const float* s1 = w_self  + (size_t)e * DD + k0;
        const float* s2 = w_punct + (size_t)e * DD + k0;
        #pragma unroll
        for (int c = 0; c < 4; ++c) {
            const int off = (e << 8) + (((k0 * 2) + (c << 4)) ^ ((e & 7) << 4));
            f32x4 a = *(const f32x4*)(s1 + c * 8);
            f32x4 d = *(const f32x4*)(s1 + c * 8 + 4);
            *(i32x4*)((char*)wsL + off) = pack8(a, d);
            f32x4 a2 = *(const f32x4*)(s2 + c * 8);
            f32x4 d2 = *(const f32x4*)(s2 + c * 8 + 4);
            *(i32x4*)((char*)wpL + off) = pack8(a2, d2);
        }
    }
    if (t < 128) { wnw_l[t] = w_nw[t]; bself_l[t] = b_self[t]; }
    __syncthreads();

    const int wave = t >> 6, lane = t & 63;
    const int wm = wave >> 2, wn = wave & 3;     // row-half / e-quarter
    const int quad = lane >> 4, l16 = lane & 15;
    const float bnw0 = b_nw[0];

    f32x4 accs[2][2];   // si, carried B->C in registers
    f32x4 yv[2][2];     // bf16-rounded yhat, carried B->C in registers

    for (int step = 0; step < 2; ++step) {
        unsigned short* yTs = step ? yT1 : yT0;

        // ---- dw = sigmoid(x . w_nw + b_nw), one row per 8-lane group ----
        {
            const int drow = wave * 8 + (lane >> 3);
            const int dseg = (lane & 7) * 16;
            const float* xr = step ? (xLf + drow * DD + dseg)
                                   : (node + (rg0 + drow) * DD + dseg);
            f32x4 a0 = *(const f32x4*)xr,        a1 = *(const f32x4*)(xr + 4);
            f32x4 a2 = *(const f32x4*)(xr + 8),  a3 = *(const f32x4*)(xr + 12);
            const float* wr = wnw_l + dseg;
            float s = a0.x*wr[0]  + a0.y*wr[1]  + a0.z*wr[2]  + a0.w*wr[3]
                    + a1.x*wr[4]  + a1.y*wr[5]  + a1.z*wr[6]  + a1.w*wr[7]
                    + a2.x*wr[8]  + a2.y*wr[9]  + a2.z*wr[10] + a2.w*wr[11]
                    + a3.x*wr[12] + a3.y*wr[13] + a3.z*wr[14] + a3.w*wr[15];
            s += __shfl_xor(s, 1, 64);
            s += __shfl_xor(s, 2, 64);
            s += __shfl_xor(s, 4, 64);
            if ((lane & 7) == 0) {
                float dv = 1.f / (1.f + __expf(-(s + bnw0)));
                dw_l[drow] = dv;
                aw[((size_t)b * 2 + step) * NN + i0 + drow] = dv;
            }
        }

        // ---- GEMMs: si = x@Ws^T, infop = x@Wp^T (64 rows x 128 e) ----
        f32x4 accp[2][2];
        #pragma unroll
        for (int mt = 0; mt < 2; ++mt)
            #pragma unroll
            for (int nt = 0; nt < 2; ++nt) {
                accs[mt][nt] = (f32x4){0.f, 0.f, 0.f, 0.f};
                accp[mt][nt] = (f32x4){0.f, 0.f, 0.f, 0.f};
            }
        #pragma unroll
        for (int kk = 0; kk < 4; ++kk) {
            const int k0 = kk * 32 + quad * 8;
            bf16x8 af[2], bs[2], bp[2];
            #pragma unroll
            for (int mt = 0; mt < 2; ++mt) {
                const int rl = wm * 32 + mt * 16 + l16;
                if (step == 0) {
                    const float* xs = node + (rg0 + rl) * DD + k0;
                    f32x4 a = *(const f32x4*)xs, c = *(const f32x4*)(xs + 4);
                    union { i32x4 i; bf16x8 h; } cv; cv.i = pack8(a, c);
                    af[mt] = cv.h;
                } else {
                    const int off = (rl << 8) + ((k0 * 2) ^ ((rl & 7) << 4));
                    af[mt] = *(const bf16x8*)((char*)xLb + off);
                }
            }
            #pragma unroll
            for (int nt = 0; nt < 2; ++nt) {
                const int e = wn * 32 + nt * 16 + l16;
                const int off = (e << 8) + ((k0 * 2) ^ ((e & 7) << 4));
                bs[nt] = *(const bf16x8*)((char*)wsL + off);
                bp[nt] = *(const bf16x8*)((char*)wpL + off);
            }
            #pragma unroll
            for (int mt = 0; mt < 2; ++mt)
                #pragma unroll
                for (int nt = 0; nt < 2; ++nt) {
                    accs[mt][nt] = __builtin_amdgcn_mfma_f32_16x16x32_bf16(af[mt], bs[nt], accs[mt][nt], 0, 0, 0);
                    accp[mt][nt] = __builtin_amdgcn_mfma_f32_16x16x32_bf16(af[mt], bp[nt], accp[mt][nt], 0, 0, 0);
                }
        }
        __syncthreads();   // dw_l ready

        // ---- B epilogue: si += bias; yhat = dw*infop (rounded); ytl ----
        #pragma unroll
        for (int mt = 0; mt < 2; ++mt)
            #pragma unroll
            for (int nt = 0; nt < 2; ++nt) {
                const int e = wn * 32 + nt * 16 + l16;
                const float bsv = bself_l[e];
                #pragma unroll
                for (int r = 0; r < 4; ++r) {
                    const int rl = wm * 32 + mt * 16 + quad * 4 + r;
                    accs[mt][nt][r] += bsv;
                    const float yval = dw_l[rl] * accp[mt][nt][r];
                    const unsigned short ub = f2bf(yval);
                    yv[mt][nt][r] = bf2f(ub);
                    ytl[e * 72 + rl] = ub;
                }
            }
        __syncthreads();
        {   // coalesced yT[step] write: [b][e][n]
            const int e2 = t >> 2, qh = t & 3;
            const i32x4* src = (const i32x4*)&ytl[e2 * 72 + qh * 16];
            i32x4 v0 = src[0], v1 = src[1];
            i32x4* dst = (i32x4*)(yTs + (size_t)(b * DD + e2) * NN + i0 + qh * 16);
            dst[0] = v0; dst[1] = v1;
        }
        __syncthreads();   // all yT stores drained (vmcnt0 at barrier)

        // ---- barrier ARRIVAL: one release RMW (single wbl2), non-blocking ----
        if (t == 0)
            __hip_atomic_fetch_add(cnt, 1u, __ATOMIC_RELEASE, __HIP_MEMORY_SCOPE_AGENT);

        if (step == 0) {
            // ---- fused ex-kernP: pack this block's 64 Ptilde rows into LDS.
            // Overlaps the barrier arrival spread (BW-bound, ~22us aggregate).
            const int* mrow = mask + (size_t)b * NN;
            int mv[32];
            #pragma unroll
            for (int w = 0; w < 32; ++w) mv[w] = mrow[w * 64 + lane];
            for (int r8 = 0; r8 < 8; ++r8) {
                const int row = wave * 8 + r8;
                const int* prow = punct + ((size_t)b * NN + i0 + row) * NN;
                unsigned p0 = 0, p1 = 0; int acc = 0;
                #pragma unroll
                for (int h = 0; h < 2; ++h) {
                    int pv[16];
                    #pragma unroll
                    for (int w = 0; w < 16; ++w) pv[w] = prow[(h * 16 + w) * 64 + lane];
                    #pragma unroll
                    for (int w = 0; w < 16; ++w) {
                        const int wg = h * 16 + w;
                        const int pred = (pv[w] & mv[wg]) & 1;
                        unsigned long long bal = __ballot(pred);
                        if (lane == wg) { p0 = (unsigned)bal; p1 = (unsigned)(bal >> 32); }
                        acc += pred;
                    }
                }
                #pragma unroll
                for (int o = 32; o > 0; o >>= 1) acc += __shfl_xor(acc, o, 64);
                if (lane < 32) {
                    uint2 w2; w2.x = p0; w2.y = p1;
                    *(uint2*)&pPk[row * 68 + 2 * lane] = w2;
                }
                if (lane == 0) nbr_l[row] = acc;
            }
            __syncthreads();  // pPk / nbr_l complete
            if (t < 64) {
                const int gi = i0 + t;                        // diagonal column
                const unsigned wd = pPk[t * 68 + (gi >> 5)];
                const int pd = (int)((wd >> (gi & 31)) & 1u);
                const int mi = mask[(size_t)b * NN + gi];
                const int nbr = nbr_l[t] - pd;
                scl_l[t] = mi ? 1.f / (float)(nbr < 1 ? 1 : nbr) : 0.f;
                pdm_l[t] = (float)pd;
            }
        }

        // ---- barrier WAIT: relaxed spin, ONE acquire on exit ----
        if (t == 0) {
            const unsigned target = 256u * (unsigned)(step + 1);
            while (__hip_atomic_load(cnt, __ATOMIC_RELAXED, __HIP_MEMORY_SCOPE_AGENT) < target)
                __builtin_amdgcn_s_sleep(4);
            (void)__hip_atomic_load(cnt, __ATOMIC_ACQUIRE, __HIP_MEMORY_SCOPE_AGENT);
        }
        __syncthreads();

        // ---- C phase: acc = Ptilde @ yhat ----
        f32x4 acc[2][2];
        #pragma unroll
        for (int mt = 0; mt < 2; ++mt)
            #pragma unroll
            for (int nt = 0; nt < 2; ++nt)
                acc[mt][nt] = (f32x4){0.f, 0.f, 0.f, 0.f};

        const unsigned short* yTb = yTs + (size_t)b * DD * NN;
        #pragma unroll 4
        for (int kk = 0; kk < 64; ++kk) {
            bf16x8 bfr[2];
            #pragma unroll
            for (int nt = 0; nt < 2; ++nt) {
                const int e = wn * 32 + nt * 16 + l16;
                bfr[nt] = *(const bf16x8*)(yTb + (size_t)e * NN + kk * 32 + quad * 8);
            }
            bf16x8 af[2];
            #pragma unroll
            for (int mt = 0; mt < 2; ++mt) {
                const unsigned w = pPk[(wm * 32 + mt * 16 + l16) * 68 + kk];
                const unsigned by = (w >> (quad * 8)) & 0xFFu;
                i32x4 ex;
                ex.x = ((by &   1u) ? 0x3F80 : 0) | ((by &   2u) ? 0x3F800000 : 0);
                ex.y = ((by &   4u) ? 0x3F80 : 0) | ((by &   8u) ? 0x3F800000 : 0);
                ex.z = ((by &  16u) ? 0x3F80 : 0) | ((by &  32u) ? 0x3F800000 : 0);
                ex.w = ((by &  64u) ? 0x3F80 : 0) | ((by & 128u) ? 0x3F800000 : 0);
                union { i32x4 i; bf16x8 h; } cv; cv.i = ex;
                af[mt] = cv.h;
            }
            #pragma unroll
            for (int mt = 0; mt < 2; ++mt)
                #pragma unroll
                for (int nt = 0; nt < 2; ++nt)
                    acc[mt][nt] = __builtin_amdgcn_mfma_f32_16x16x32_bf16(af[mt], bfr[nt], acc[mt][nt], 0, 0, 0);
        }

        // ---- C epilogue: x = relu(si + scale*(acc - pdm*yhat_i)) ----
        #pragma unroll
        for (int mt = 0; mt < 2; ++mt)
            #pragma unroll
            for (int nt = 0; nt < 2; ++nt) {
                const int e = wn * 32 + nt * 16 + l16;
                #pragma unroll
                for (int r = 0; r < 4; ++r) {
                    const int rl = wm * 32 + mt * 16 + quad * 4 + r;
                    float v = accs[mt][nt][r] + scl_l[rl] * (acc[mt][nt][r] - pdm_l[rl] * yv[mt][nt][r]);
                    v = fmaxf(v, 0.f);
                    if (step == 0) {
                        xLf[rl * DD + e] = v;
                        const int off = (rl << 8) + ((e * 2) ^ ((rl & 7) << 4));
                        *(unsigned short*)((char*)xLb + off) = f2bf(v);
                    } else {
                        x_out[(rg0 + rl) * DD + e] = v;
                    }
                }
            }
        if (step == 0) __syncthreads();   // xLf/xLb ready for step-1 B phase
    }
}

extern "C" void kernel_launch(void* const* d_in, const int* in_sizes, int n_in,
                              void* d_out, int out_size, void* d_ws, size_t ws_size,
                              hipStream_t stream) {
    const float* node   = (const float*)d_in[0];
    const int*   mask   = (const int*)  d_in[1];
    const int*   punct  = (const int*)  d_in[2];
    const float* w_nw   = (const float*)d_in[3];
    const float* b_nw   = (const float*)d_in[4];
    const float* w_self = (const float*)d_in[5];
    const float* b_self = (const float*)d_in[6];
    const float* w_punct= (const float*)d_in[7];

    float* xout = (float*)d_out;
    float* aw   = xout + (size_t)BB * NN * DD;

    char* w = (char*)d_ws;
    unsigned short* yT0 = (unsigned short*)w;                    // 4 MB
    unsigned short* yT1 = (unsigned short*)(w + (4u << 20));     // 4 MB
    unsigned*       cnt = (unsigned*)(w + (8u << 20));           // 4 B

    static bool attrSet = false;
    if (!attrSet) {
        hipFuncSetAttribute(reinterpret_cast<const void*>(kernF),
                            hipFuncAttributeMaxDynamicSharedMemorySize, SMEM_BYTES);
        attrSet = true;
    }

    hipMemsetAsync(cnt, 0, sizeof(unsigned), stream);
    kernF<<<dim3(256), dim3(512), SMEM_BYTES, stream>>>(
        node, mask, punct, w_nw, b_nw, w_self, b_self, w_punct,
        yT0, yT1, xout, aw, cnt);
}

// Round 4
// 299.676 us; speedup vs baseline: 1.1582x; 1.0671x over previous
//
#include <hip/hip_runtime.h>
#include <hip/hip_bf16.h>

#define BB 8
#define NN 2048
#define DD 128

typedef __attribute__((ext_vector_type(8))) __bf16 bf16x8;
typedef __attribute__((ext_vector_type(4))) float f32x4;
typedef __attribute__((ext_vector_type(4))) int   i32x4;

static __device__ __forceinline__ unsigned short f2bf(float f) {
    union { float f; unsigned u; } v; v.f = f;
    unsigned r = (v.u + 0x7FFFu + ((v.u >> 16) & 1u)) >> 16;
    return (unsigned short)r;
}
static __device__ __forceinline__ float bf2f(unsigned short b) {
    union { unsigned u; float f; } v; v.u = ((unsigned)b) << 16;
    return v.f;
}

// ---------------------------------------------------------------------------
// kernB body (R0-proven structure, verbatim): per 64-row tile, MFMA GEMMs
// si = x@W_self^T + b_self, infop = x@W_punct^T; fused dw = sigmoid(x.w_nw
// + b_nw); writes si f32, yhat = dw*infop bf16 in [n][e] and transposed
// [e][n]. PRECONV=true loads bf16 weights (wsb/wpb) instead of converting
// f32 (same f2bf values -> bit-identical).
// ---------------------------------------------------------------------------
template <bool PRECONV>
static __device__ __forceinline__ void kernB_body(
    int n0, const float* __restrict__ x,
    const float* __restrict__ w_nw,  const float* __restrict__ b_nw,
    const void* __restrict__ wself_p, const float* __restrict__ b_self,
    const void* __restrict__ wpunct_p,
    float* __restrict__ si_out,
    unsigned short* __restrict__ yne_out,   // [B*N][D] bf16
    unsigned short* __restrict__ yT_out,    // [B][D][N] bf16
    float* __restrict__ aw_out)             // + step*N already applied
{
    __shared__ unsigned short xt[64*32];
    __shared__ unsigned short wst[128*32];
    __shared__ unsigned short wpt[128*32];
    __shared__ float wnw_l[DD];
    __shared__ float red[256];
    __shared__ float dw_l[64];
    __shared__ unsigned short ytl[128*72];

    const int t  = threadIdx.x;
    const int b  = n0 >> 11;
    const int nb = n0 & (NN - 1);

    if (t < DD) wnw_l[t] = w_nw[t];
    __syncthreads();

    const int wave = t >> 6, lane = t & 63;
    const int wm = wave >> 1, wn = wave & 1;
    const int quad = lane >> 4, l16 = lane & 15;

    const int n_loc = t >> 2, dq = t & 3;
    const int we = t >> 1,   wh = t & 1;

    f32x4 accs[2][4] = {}; f32x4 accp[2][4] = {};
    float dwpart = 0.f;

    #pragma unroll
    for (int kk = 0; kk < 4; ++kk) {
        const int k0 = kk * 32;
        {
            const float* xs = x + (size_t)(n0 + n_loc) * DD + k0 + dq * 8;
            f32x4 a = *(const f32x4*)xs;
            f32x4 c = *(const f32x4*)(xs + 4);
            const float* wv = &wnw_l[k0 + dq * 8];
            dwpart += a.x*wv[0] + a.y*wv[1] + a.z*wv[2] + a.w*wv[3]
                    + c.x*wv[4] + c.y*wv[5] + c.z*wv[6] + c.w*wv[7];
            unsigned q0 = f2bf(a.x) | ((unsigned)f2bf(a.y) << 16);
            unsigned q1 = f2bf(a.z) | ((unsigned)f2bf(a.w) << 16);
            unsigned q2 = f2bf(c.x) | ((unsigned)f2bf(c.y) << 16);
            unsigned q3 = f2bf(c.z) | ((unsigned)f2bf(c.w) << 16);
            i32x4 pw = {(int)q0,(int)q1,(int)q2,(int)q3};
            *(i32x4*)&xt[n_loc*32 + dq*8] = pw;
        }
        if (PRECONV) {
            const unsigned short* s1 = (const unsigned short*)wself_p  + (size_t)we * DD + k0 + wh*16;
            const unsigned short* s2 = (const unsigned short*)wpunct_p + (size_t)we * DD + k0 + wh*16;
            i32x4 a0 = *(const i32x4*)s1;
            i32x4 a1 = *(const i32x4*)(s1 + 8);
            *(i32x4*)&wst[we*32 + wh*16]     = a0;
            *(i32x4*)&wst[we*32 + wh*16 + 8] = a1;
            i32x4 c0 = *(const i32x4*)s2;
            i32x4 c1 = *(const i32x4*)(s2 + 8);
            *(i32x4*)&wpt[we*32 + wh*16]     = c0;
            *(i32x4*)&wpt[we*32 + wh*16 + 8] = c1;
        } else {
            const float* s1 = (const float*)wself_p  + (size_t)we * DD + k0 + wh*16;
            const float* s2 = (const float*)wpunct_p + (size_t)we * DD + k0 + wh*16;
            f32x4 a0 = *(const f32x4*)s1;      f32x4 a1 = *(const f32x4*)(s1+4);
            f32x4 a2 = *(const f32x4*)(s1+8);  f32x4 a3 = *(const f32x4*)(s1+12);
            unsigned q0 = f2bf(a0.x) | ((unsigned)f2bf(a0.y)<<16);
            unsigned q1 = f2bf(a0.z) | ((unsigned)f2bf(a0.w)<<16);
            unsigned q2 = f2bf(a1.x) | ((unsigned)f2bf(a1.y)<<16);
            unsigned q3 = f2bf(a1.z) | ((unsigned)f2bf(a1.w)<<16);
            unsigned q4 = f2bf(a2.x) | ((unsigned)f2bf(a2.y)<<16);
            unsigned q5 = f2bf(a2.z) | ((unsigned)f2bf(a2.w)<<16);
            unsigned q6 = f2bf(a3.x) | ((unsigned)f2bf(a3.y)<<16);
            unsigned q7 = f2bf(a3.z) | ((unsigned)f2bf(a3.w)<<16);
            i32x4 pw0 = {(int)q0,(int)q1,(int)q2,(int)q3};
            i32x4 pw1 = {(int)q4,(int)q5,(int)q6,(int)q7};
            *(i32x4*)&wst[we*32 + wh*16]     = pw0;
            *(i32x4*)&wst[we*32 + wh*16 + 8] = pw1;
            f32x4 c0 = *(const f32x4*)s2;      f32x4 c1 = *(const f32x4*)(s2+4);
            f32x4 c2 = *(const f32x4*)(s2+8);  f32x4 c3 = *(const f32x4*)(s2+12);
            unsigned r0 = f2bf(c0.x) | ((unsigned)f2bf(c0.y)<<16);
            unsigned r1 = f2bf(c0.z) | ((unsigned)f2bf(c0.w)<<16);
            unsigned r2 = f2bf(c1.x) | ((unsigned)f2bf(c1.y)<<16);
            unsigned r3 = f2bf(c1.z) | ((unsigned)f2bf(c1.w)<<16);
            unsigned r4 = f2bf(c2.x) | ((unsigned)f2bf(c2.y)<<16);
            unsigned r5 = f2bf(c2.z) | ((unsigned)f2bf(c2.w)<<16);
            unsigned r6 = f2bf(c3.x) | ((unsigned)f2bf(c3.y)<<16);
            unsigned r7 = f2bf(c3.z) | ((unsigned)f2bf(c3.w)<<16);
            i32x4 pv0 = {(int)r0,(int)r1,(int)r2,(int)r3};
            i32x4 pv1 = {(int)r4,(int)r5,(int)r6,(int)r7};
            *(i32x4*)&wpt[we*32 + wh*16]     = pv0;
            *(i32x4*)&wpt[we*32 + wh*16 + 8] = pv1;
        }
        __syncthreads();
        bf16x8 af[2], bs[4], bp[4];
        #pragma unroll
        for (int mt = 0; mt < 2; ++mt)
            af[mt] = *(const bf16x8*)&xt[(wm*32 + mt*16 + l16)*32 + quad*8];
        #pragma unroll
        for (int nt = 0; nt < 4; ++nt) {
            const int er = wn*64 + nt*16 + l16;
            bs[nt] = *(const bf16x8*)&wst[er*32 + quad*8];
            bp[nt] = *(const bf16x8*)&wpt[er*32 + quad*8];
        }
        #pragma unroll
        for (int mt = 0; mt < 2; ++mt)
            #pragma unroll
            for (int nt = 0; nt < 4; ++nt) {
                accs[mt][nt] = __builtin_amdgcn_mfma_f32_16x16x32_bf16(af[mt], bs[nt], accs[mt][nt], 0, 0, 0);
                accp[mt][nt] = __builtin_amdgcn_mfma_f32_16x16x32_bf16(af[mt], bp[nt], accp[mt][nt], 0, 0, 0);
            }
        __syncthreads();
    }

    red[t] = dwpart;
    __syncthreads();
    if (t < 64) {
        float s = red[4*t] + red[4*t+1] + red[4*t+2] + red[4*t+3] + b_nw[0];
        float dv = 1.f / (1.f + __expf(-s));
        dw_l[t] = dv;
        aw_out[(size_t)b * 2 * NN + nb + t] = dv;
    }
    __syncthreads();

    #pragma unroll
    for (int mt = 0; mt < 2; ++mt) {
        #pragma unroll
        for (int nt = 0; nt < 4; ++nt) {
            const int e = wn*64 + nt*16 + l16;
            const float bsv = b_self[e];
            #pragma unroll
            for (int r = 0; r < 4; ++r) {
                const int nl = wm*32 + mt*16 + quad*4 + r;
                const size_t idx = (size_t)(n0 + nl) * DD + e;
                si_out[idx] = accs[mt][nt][r] + bsv;
                const float yv = dw_l[nl] * accp[mt][nt][r];
                const unsigned short ub = f2bf(yv);
                yne_out[idx] = ub;
                ytl[e*72 + nl] = ub;
            }
        }
    }
    __syncthreads();
    {
        const int e = t >> 1, half = t & 1;
        const i32x4* src = (const i32x4*)&ytl[e*72 + half*32];
        i32x4 v0 = src[0], v1 = src[1], v2 = src[2], v3 = src[3];
        i32x4* dst = (i32x4*)(yT_out + (size_t)(b*DD + e) * NN + nb + half*32);
        dst[0] = v0; dst[1] = v1; dst[2] = v2; dst[3] = v3;
    }
}

// ---------------------------------------------------------------------------
// kern0: heterogeneous launch overlapping three INDEPENDENT phases:
//   bid <  256: B0 (step-0 kernB, x = node, self-contained f32 weight conv)
//   256<=bid<272: weight f32->bf16 conversion (wsb/wpb for B1)
//   bid >= 272: Ptilde bit-pack (ex-kernP, 4096 blocks, HBM-bound)
// B0 blocks dispatch FIRST (one per CU), pack blocks fill remaining slots ->
// the ~21us HBM-bound pack streams underneath B0's compute.
// ---------------------------------------------------------------------------
__global__ __launch_bounds__(256) void kern0(
    const int* __restrict__ punct, const int* __restrict__ mask,
    const float* __restrict__ node,
    const float* __restrict__ w_nw, const float* __restrict__ b_nw,
    const float* __restrict__ w_self, const float* __restrict__ b_self,
    const float* __restrict__ w_punct,
    unsigned* __restrict__ pk, float* __restrict__ scale_g, float* __restrict__ pdm_g,
    unsigned short* __restrict__ wsb, unsigned short* __restrict__ wpb,
    float* __restrict__ si, unsigned short* __restrict__ yne,
    unsigned short* __restrict__ yT, float* __restrict__ aw)
{
    const int bid = blockIdx.x;
    const int t = threadIdx.x;

    if (bid < 256) {
        kernB_body<false>(bid * 64, node, w_nw, b_nw, w_self, b_self, w_punct,
                          si, yne, yT, aw);
        return;
    }
    if (bid < 272) {
        const int cb = bid - 256;
        const float* src = (cb < 8) ? w_self : w_punct;
        unsigned short* dst = (cb < 8) ? wsb : wpb;
        const size_t i0 = (size_t)(cb & 7) * 2048 + (size_t)t * 8;
        f32x4 a = *(const f32x4*)(src + i0);
        f32x4 c = *(const f32x4*)(src + i0 + 4);
        unsigned q0 = f2bf(a.x) | ((unsigned)f2bf(a.y) << 16);
        unsigned q1 = f2bf(a.z) | ((unsigned)f2bf(a.w) << 16);
        unsigned q2 = f2bf(c.x) | ((unsigned)f2bf(c.y) << 16);
        unsigned q3 = f2bf(c.z) | ((unsigned)f2bf(c.w) << 16);
        i32x4 pw = {(int)q0, (int)q1, (int)q2, (int)q3};
        *(i32x4*)(dst + i0) = pw;
        return;
    }

    // ---- Ptilde pack (R0 kernP body, proven) ----
    const int wave = t >> 6, lane = t & 63;
    const int row_g = (bid - 272) * 4 + wave;       // 0..16383
    const int b = row_g >> 11;
    const int i = row_g & (NN - 1);

    const int* prow = punct + (size_t)row_g * NN;
    const int* mrow = mask + (size_t)b * NN;

    unsigned pk0 = 0, pk1 = 0;
    int acc = 0;
    #pragma unroll 4
    for (int w = 0; w < 32; ++w) {
        const int col = w * 64 + lane;
        const int p = prow[col];
        const int m = mrow[col];
        const int pred = (p & m) & 1;
        unsigned long long bal = __ballot(pred);
        if (lane == w) { pk0 = (unsigned)bal; pk1 = (unsigned)(bal >> 32); }
        acc += pred + ((col == i ? pred : 0) << 16);
    }
    #pragma unroll
    for (int o = 32; o > 0; o >>= 1) acc += __shfl_xor(acc, o, 64);

    if (lane < 32) {
        uint2 w2; w2.x = pk0; w2.y = pk1;
        *(uint2*)(pk + (size_t)row_g * 64 + 2 * lane) = w2;
    }
    if (lane == 0) {
        const int nall = acc & 0xFFFF;
        const int pdm  = acc >> 16;
        const int mi   = mrow[i];
        const int nbr  = nall - pdm;
        scale_g[row_g] = mi ? 1.f / (float)(nbr < 1 ? 1 : nbr) : 0.f;
        pdm_g[row_g]   = (float)pdm;
    }
}

// kernB1: step-1 B with preconverted bf16 weights.
__global__ __launch_bounds__(256) void kernB1(
    const float* __restrict__ x,
    const unsigned short* __restrict__ wsb, const unsigned short* __restrict__ wpb,
    const float* __restrict__ w_nw, const float* __restrict__ b_nw,
    const float* __restrict__ b_self,
    float* __restrict__ si, unsigned short* __restrict__ yne,
    unsigned short* __restrict__ yT, float* __restrict__ aw1)
{
    kernB_body<true>(blockIdx.x * 64, x, w_nw, b_nw, wsb, b_self, wpb,
                     si, yne, yT, aw1);
}

// ---------------------------------------------------------------------------
// kernC (R0-proven structure): agg = Ptilde @ yhat, Ptilde from packed bits
// (LDS-resident), B-fragments direct from yT. ZERO barriers in the K-loop.
// Round-4 delta: XCD-aware mapping b = blockIdx&7 (bijective, 256%8==0) ->
// the 32 blocks sharing batch-b's 512KB yT panel land on one XCD (L2 reuse).
// Epilogue: x = relu(si + scale*(acc - pdm*yhat_i)).
// ---------------------------------------------------------------------------
__global__ __launch_bounds__(256) void kernC(
    const unsigned* __restrict__ pk,        // [B*N][64] packed bits
    const float* __restrict__ scale_g, const float* __restrict__ pdm_g,
    const unsigned short* __restrict__ yT,  // [B][D][N] bf16
    const float* __restrict__ si,           // [B*N][D]
    const unsigned short* __restrict__ yne, // [B*N][D] bf16
    float* __restrict__ x_out)              // [B*N][D]
{
    __shared__ unsigned pPk[64 * 68];       // 64 rows x 64 words, pad 68
    __shared__ float scale_l[64];
    __shared__ float pdm_l[64];

    const int t  = threadIdx.x;
    const int b  = blockIdx.x & 7;          // XCD-aware batch mapping
    const int i0 = (blockIdx.x >> 3) * 64;
    const size_t rg0 = (size_t)b * NN + i0;

    #pragma unroll
    for (int r = 0; r < 4; ++r) {
        const int u   = r * 256 + t;
        const int row = u >> 4;
        const int wq  = (u & 15) * 4;
        i32x4 v = *(const i32x4*)(pk + (rg0 + row) * 64 + wq);
        *(i32x4*)&pPk[row * 68 + wq] = v;
    }
    if (t < 64) {
        scale_l[t] = scale_g[rg0 + t];
        pdm_l[t]   = pdm_g[rg0 + t];
    }
    __syncthreads();

    const int wn = t >> 6, lane = t & 63;
    const int quad = lane >> 4, l16 = lane & 15;
    const unsigned short* yTb = yT + (size_t)b * DD * NN;

    f32x4 acc[4][2] = {};

    #pragma unroll 4
    for (int kk = 0; kk < 64; ++kk) {
        bf16x8 bfr[2];
        #pragma unroll
        for (int nt = 0; nt < 2; ++nt) {
            const int e = wn*32 + nt*16 + l16;
            bfr[nt] = *(const bf16x8*)(yTb + (size_t)e * NN + kk*32 + quad*8);
        }
        bf16x8 af[4];
        #pragma unroll
        for (int mt = 0; mt < 4; ++mt) {
            const unsigned w = pPk[(mt*16 + l16) * 68 + kk];
            const unsigned by = (w >> (quad * 8)) & 0xFFu;
            i32x4 ex;
            ex.x = ((by &   1u) ? 0x3F80 : 0) | ((by &   2u) ? 0x3F800000 : 0);
            ex.y = ((by &   4u) ? 0x3F80 : 0) | ((by &   8u) ? 0x3F800000 : 0);
            ex.z = ((by &  16u) ? 0x3F80 : 0) | ((by &  32u) ? 0x3F800000 : 0);
            ex.w = ((by &  64u) ? 0x3F80 : 0) | ((by & 128u) ? 0x3F800000 : 0);
            union { i32x4 i; bf16x8 h; } cv; cv.i = ex;
            af[mt] = cv.h;
        }
        #pragma unroll
        for (int mt = 0; mt < 4; ++mt)
            #pragma unroll
            for (int nt = 0; nt < 2; ++nt)
                acc[mt][nt] = __builtin_amdgcn_mfma_f32_16x16x32_bf16(af[mt], bfr[nt], acc[mt][nt], 0, 0, 0);
    }

    #pragma unroll
    for (int mt = 0; mt < 4; ++mt) {
        #pragma unroll
        for (int nt = 0; nt < 2; ++nt) {
            const int e = wn*32 + nt*16 + l16;
            #pragma unroll
            for (int r = 0; r < 4; ++r) {
                const int row = mt*16 + quad*4 + r;
                const size_t idx = (rg0 + row) * DD + e;
                const float yv = bf2f(yne[idx]);
                float v = si[idx] + scale_l[row] * (acc[mt][nt][r] - pdm_l[row] * yv);
                x_out[idx] = fmaxf(v, 0.f);
            }
        }
    }
}

extern "C" void kernel_launch(void* const* d_in, const int* in_sizes, int n_in,
                              void* d_out, int out_size, void* d_ws, size_t ws_size,
                              hipStream_t stream) {
    const float* node   = (const float*)d_in[0];
    const int*   mask   = (const int*)  d_in[1];
    const int*   punct  = (const int*)  d_in[2];
    const float* w_nw   = (const float*)d_in[3];
    const float* b_nw   = (const float*)d_in[4];
    const float* w_self = (const float*)d_in[5];
    const float* b_self = (const float*)d_in[6];
    const float* w_punct= (const float*)d_in[7];

    float* xout = (float*)d_out;
    float* aw   = xout + (size_t)BB * NN * DD;

    char* w = (char*)d_ws;
    float*          si   = (float*)w;                               // 8 MB
    unsigned short* yne  = (unsigned short*)(w + (8u  << 20));      // 4 MB
    unsigned short* yT   = (unsigned short*)(w + (12u << 20));      // 4 MB
    unsigned*       pk   = (unsigned*)(w + (16u << 20));            // 4 MB
    float*          scl  = (float*)(w + (20u << 20));               // 64 KB
    float*          pdm  = (float*)(w + (20u << 20) + (64u << 10)); // 64 KB
    unsigned short* wsb  = (unsigned short*)(w + (21u << 20));      // 32 KB
    unsigned short* wpb  = (unsigned short*)(w + (21u << 20) + (32u << 10)); // 32 KB

    dim3 blk(256);
    // P + weight-conv + B0 overlapped in one heterogeneous launch
    kern0<<<dim3(4368), blk, 0, stream>>>(punct, mask, node, w_nw, b_nw,
                                          w_self, b_self, w_punct,
                                          pk, scl, pdm, wsb, wpb,
                                          si, yne, yT, aw);
    kernC<<<dim3(256), blk, 0, stream>>>(pk, scl, pdm, yT, si, yne, xout);
    kernB1<<<dim3(256), blk, 0, stream>>>(xout, wsb, wpb, w_nw, b_nw, b_self,
                                          si, yne, yT, aw + NN);
    kernC<<<dim3(256), blk, 0, stream>>>(pk, scl, pdm, yT, si, yne, xout);
}

// Round 5
// 288.998 us; speedup vs baseline: 1.2010x; 1.0369x over previous
//
#include <hip/hip_runtime.h>
#include <hip/hip_bf16.h>

#define BB 8
#define NN 2048
#define DD 128

typedef __attribute__((ext_vector_type(8))) __bf16 bf16x8;
typedef __attribute__((ext_vector_type(4))) float f32x4;
typedef __attribute__((ext_vector_type(4))) int   i32x4;

static __device__ __forceinline__ unsigned short f2bf(float f) {
    union { float f; unsigned u; } v; v.f = f;
    unsigned r = (v.u + 0x7FFFu + ((v.u >> 16) & 1u)) >> 16;
    return (unsigned short)r;
}
static __device__ __forceinline__ float bf2f(unsigned short b) {
    union { unsigned u; float f; } v; v.u = ((unsigned)b) << 16;
    return v.f;
}

// ---------------------------------------------------------------------------
// kernP2: latency-optimized Ptilde bit-pack.
//   R0's kernP was latency-bound (~55-60us, 1.1TB/s, VALUBusy 15%): 64 scalar
//   dword loads/row in 8 serialized unroll-4 batches + 32 divergent ballot
//   captures. Rewrite: 8 independent dwordx4 loads/row (ONE latency wall),
//   nibble-per-lane bit-pack + 3-step shfl_xor butterfly, mask pre-packed to
//   one reg/wave, popcount via __popc. Zero LDS -> 8 blocks/CU.
//   2048 blocks x 4 waves x 2 rows = 16384 rows. Blocks >= 2048: weight
//   f32->bf16 conversion (wsb/wpb) for kernB1 (same f2bf -> bit-identical).
// Output word layout identical to ballot version: word kk bit p = col kk*32+p.
// ---------------------------------------------------------------------------
__global__ __launch_bounds__(256) void kernP2(
    const int* __restrict__ punct, const int* __restrict__ mask,
    const float* __restrict__ w_self, const float* __restrict__ w_punct,
    unsigned* __restrict__ pk, float* __restrict__ scale_g, float* __restrict__ pdm_g,
    unsigned short* __restrict__ wsb, unsigned short* __restrict__ wpb)
{
    const int bid = blockIdx.x;
    const int t = threadIdx.x;

    if (bid >= 2048) {   // weight conversion tail
        const int cb = bid - 2048;
        const float* src = (cb < 8) ? w_self : w_punct;
        unsigned short* dst = (cb < 8) ? wsb : wpb;
        const size_t i0 = (size_t)(cb & 7) * 2048 + (size_t)t * 8;
        f32x4 a = *(const f32x4*)(src + i0);
        f32x4 c = *(const f32x4*)(src + i0 + 4);
        unsigned q0 = f2bf(a.x) | ((unsigned)f2bf(a.y) << 16);
        unsigned q1 = f2bf(a.z) | ((unsigned)f2bf(a.w) << 16);
        unsigned q2 = f2bf(c.x) | ((unsigned)f2bf(c.y) << 16);
        unsigned q3 = f2bf(c.z) | ((unsigned)f2bf(c.w) << 16);
        i32x4 pw = {(int)q0, (int)q1, (int)q2, (int)q3};
        *(i32x4*)(dst + i0) = pw;
        return;
    }

    const int wave = t >> 6, lane = t & 63;
    const int row0 = bid * 8 + wave * 2;            // 2 rows per wave
    const int b = row0 >> 11;                       // same batch for whole block
    const int* mrow = mask + (size_t)b * NN;

    // ---- pre-pack mask: 8 nibbles (one per 256-col group) in one register --
    unsigned mreg = 0;
    #pragma unroll
    for (int g = 0; g < 8; ++g) {
        i32x4 m = *(const i32x4*)(mrow + g * 256 + lane * 4);
        unsigned nib = (m.x & 1) | ((m.y & 1) << 1) | ((m.z & 1) << 2) | ((m.w & 1) << 3);
        mreg |= nib << (4 * g);
    }

    #pragma unroll
    for (int r = 0; r < 2; ++r) {
        const int row = row0 + r;
        const int i = row & (NN - 1);               // diagonal column
        const int* prow = punct + (size_t)row * NN;
        unsigned* pkrow = pk + (size_t)row * 64;

        int acc = 0;
        #pragma unroll
        for (int g = 0; g < 8; ++g) {
            i32x4 v = *(const i32x4*)(prow + g * 256 + lane * 4);
            unsigned nib = (v.x & 1) | ((v.y & 1) << 1) | ((v.z & 1) << 2) | ((v.w & 1) << 3);
            nib &= (mreg >> (4 * g)) & 0xFu;
            acc += __popc(nib);
            // diagonal bit (masked): col i in this lane's 4-col range?
            if (((i >> 8) == g) && (((i >> 2) & 63) == lane))
                acc += (int)((nib >> (i & 3)) & 1u) << 16;
            // butterfly combine: nibble -> byte -> half -> word (LSB = low col)
            unsigned p1 = __shfl_xor(nib, 1, 64);
            unsigned lo = (lane & 1) ? p1 : nib, hi = (lane & 1) ? nib : p1;
            unsigned by = lo | (hi << 4);
            unsigned p2 = __shfl_xor(by, 2, 64);
            lo = (lane & 2) ? p2 : by; hi = (lane & 2) ? by : p2;
            unsigned hf = lo | (hi << 8);
            unsigned p4 = __shfl_xor(hf, 4, 64);
            lo = (lane & 4) ? p4 : hf; hi = (lane & 4) ? hf : p4;
            unsigned wd = lo | (hi << 16);
            if ((lane & 7) == 0) pkrow[g * 8 + (lane >> 3)] = wd;
        }
        // wave reduce: low 16 bits = row popcount, bit16 = masked diagonal
        #pragma unroll
        for (int o = 32; o > 0; o >>= 1) acc += __shfl_xor(acc, o, 64);
        if (lane == 0) {
            const int nall = acc & 0xFFFF;
            const int pdm  = acc >> 16;
            const int mi   = mrow[i];
            const int nbr  = nall - pdm;
            scale_g[row] = mi ? 1.f / (float)(nbr < 1 ? 1 : nbr) : 0.f;
            pdm_g[row]   = (float)pdm;
        }
    }
}

// ---------------------------------------------------------------------------
// kernB body (R0-proven structure): per 64-row tile, MFMA GEMMs
// si = x@W_self^T + b_self, infop = x@W_punct^T; fused dw = sigmoid(x.w_nw
// + b_nw); writes si f32, yhat = dw*infop bf16 in [n][e] and transposed
// [e][n]. PRECONV=true loads bf16 weights (wsb/wpb) instead of converting
// f32 (same f2bf values -> bit-identical).
// ---------------------------------------------------------------------------
template <bool PRECONV>
static __device__ __forceinline__ void kernB_body(
    int n0, const float* __restrict__ x,
    const float* __restrict__ w_nw,  const float* __restrict__ b_nw,
    const void* __restrict__ wself_p, const float* __restrict__ b_self,
    const void* __restrict__ wpunct_p,
    float* __restrict__ si_out,
    unsigned short* __restrict__ yne_out,   // [B*N][D] bf16
    unsigned short* __restrict__ yT_out,    // [B][D][N] bf16
    float* __restrict__ aw_out)             // + step*N already applied
{
    __shared__ unsigned short xt[64*32];
    __shared__ unsigned short wst[128*32];
    __shared__ unsigned short wpt[128*32];
    __shared__ float wnw_l[DD];
    __shared__ float red[256];
    __shared__ float dw_l[64];
    __shared__ unsigned short ytl[128*72];

    const int t  = threadIdx.x;
    const int b  = n0 >> 11;
    const int nb = n0 & (NN - 1);

    if (t < DD) wnw_l[t] = w_nw[t];
    __syncthreads();

    const int wave = t >> 6, lane = t & 63;
    const int wm = wave >> 1, wn = wave & 1;
    const int quad = lane >> 4, l16 = lane & 15;

    const int n_loc = t >> 2, dq = t & 3;
    const int we = t >> 1,   wh = t & 1;

    f32x4 accs[2][4] = {}; f32x4 accp[2][4] = {};
    float dwpart = 0.f;

    #pragma unroll
    for (int kk = 0; kk < 4; ++kk) {
        const int k0 = kk * 32;
        {
            const float* xs = x + (size_t)(n0 + n_loc) * DD + k0 + dq * 8;
            f32x4 a = *(const f32x4*)xs;
            f32x4 c = *(const f32x4*)(xs + 4);
            const float* wv = &wnw_l[k0 + dq * 8];
            dwpart += a.x*wv[0] + a.y*wv[1] + a.z*wv[2] + a.w*wv[3]
                    + c.x*wv[4] + c.y*wv[5] + c.z*wv[6] + c.w*wv[7];
            unsigned q0 = f2bf(a.x) | ((unsigned)f2bf(a.y) << 16);
            unsigned q1 = f2bf(a.z) | ((unsigned)f2bf(a.w) << 16);
            unsigned q2 = f2bf(c.x) | ((unsigned)f2bf(c.y) << 16);
            unsigned q3 = f2bf(c.z) | ((unsigned)f2bf(c.w) << 16);
            i32x4 pw = {(int)q0,(int)q1,(int)q2,(int)q3};
            *(i32x4*)&xt[n_loc*32 + dq*8] = pw;
        }
        if (PRECONV) {
            const unsigned short* s1 = (const unsigned short*)wself_p  + (size_t)we * DD + k0 + wh*16;
            const unsigned short* s2 = (const unsigned short*)wpunct_p + (size_t)we * DD + k0 + wh*16;
            i32x4 a0 = *(const i32x4*)s1;
            i32x4 a1 = *(const i32x4*)(s1 + 8);
            *(i32x4*)&wst[we*32 + wh*16]     = a0;
            *(i32x4*)&wst[we*32 + wh*16 + 8] = a1;
            i32x4 c0 = *(const i32x4*)s2;
            i32x4 c1 = *(const i32x4*)(s2 + 8);
            *(i32x4*)&wpt[we*32 + wh*16]     = c0;
            *(i32x4*)&wpt[we*32 + wh*16 + 8] = c1;
        } else {
            const float* s1 = (const float*)wself_p  + (size_t)we * DD + k0 + wh*16;
            const float* s2 = (const float*)wpunct_p + (size_t)we * DD + k0 + wh*16;
            f32x4 a0 = *(const f32x4*)s1;      f32x4 a1 = *(const f32x4*)(s1+4);
            f32x4 a2 = *(const f32x4*)(s1+8);  f32x4 a3 = *(const f32x4*)(s1+12);
            unsigned q0 = f2bf(a0.x) | ((unsigned)f2bf(a0.y)<<16);
            unsigned q1 = f2bf(a0.z) | ((unsigned)f2bf(a0.w)<<16);
            unsigned q2 = f2bf(a1.x) | ((unsigned)f2bf(a1.y)<<16);
            unsigned q3 = f2bf(a1.z) | ((unsigned)f2bf(a1.w)<<16);
            unsigned q4 = f2bf(a2.x) | ((unsigned)f2bf(a2.y)<<16);
            unsigned q5 = f2bf(a2.z) | ((unsigned)f2bf(a2.w)<<16);
            unsigned q6 = f2bf(a3.x) | ((unsigned)f2bf(a3.y)<<16);
            unsigned q7 = f2bf(a3.z) | ((unsigned)f2bf(a3.w)<<16);
            i32x4 pw0 = {(int)q0,(int)q1,(int)q2,(int)q3};
            i32x4 pw1 = {(int)q4,(int)q5,(int)q6,(int)q7};
            *(i32x4*)&wst[we*32 + wh*16]     = pw0;
            *(i32x4*)&wst[we*32 + wh*16 + 8] = pw1;
            f32x4 c0 = *(const f32x4*)s2;      f32x4 c1 = *(const f32x4*)(s2+4);
            f32x4 c2 = *(const f32x4*)(s2+8);  f32x4 c3 = *(const f32x4*)(s2+12);
            unsigned r0 = f2bf(c0.x) | ((unsigned)f2bf(c0.y)<<16);
            unsigned r1 = f2bf(c0.z) | ((unsigned)f2bf(c0.w)<<16);
            unsigned r2 = f2bf(c1.x) | ((unsigned)f2bf(c1.y)<<16);
            unsigned r3 = f2bf(c1.z) | ((unsigned)f2bf(c1.w)<<16);
            unsigned r4 = f2bf(c2.x) | ((unsigned)f2bf(c2.y)<<16);
            unsigned r5 = f2bf(c2.z) | ((unsigned)f2bf(c2.w)<<16);
            unsigned r6 = f2bf(c3.x) | ((unsigned)f2bf(c3.y)<<16);
            unsigned r7 = f2bf(c3.z) | ((unsigned)f2bf(c3.w)<<16);
            i32x4 pv0 = {(int)r0,(int)r1,(int)r2,(int)r3};
            i32x4 pv1 = {(int)r4,(int)r5,(int)r6,(int)r7};
            *(i32x4*)&wpt[we*32 + wh*16]     = pv0;
            *(i32x4*)&wpt[we*32 + wh*16 + 8] = pv1;
        }
        __syncthreads();
        bf16x8 af[2], bs[4], bp[4];
        #pragma unroll
        for (int mt = 0; mt < 2; ++mt)
            af[mt] = *(const bf16x8*)&xt[(wm*32 + mt*16 + l16)*32 + quad*8];
        #pragma unroll
        for (int nt = 0; nt < 4; ++nt) {
            const int er = wn*64 + nt*16 + l16;
            bs[nt] = *(const bf16x8*)&wst[er*32 + quad*8];
            bp[nt] = *(const bf16x8*)&wpt[er*32 + quad*8];
        }
        #pragma unroll
        for (int mt = 0; mt < 2; ++mt)
            #pragma unroll
            for (int nt = 0; nt < 4; ++nt) {
                accs[mt][nt] = __builtin_amdgcn_mfma_f32_16x16x32_bf16(af[mt], bs[nt], accs[mt][nt], 0, 0, 0);
                accp[mt][nt] = __builtin_amdgcn_mfma_f32_16x16x32_bf16(af[mt], bp[nt], accp[mt][nt], 0, 0, 0);
            }
        __syncthreads();
    }

    red[t] = dwpart;
    __syncthreads();
    if (t < 64) {
        float s = red[4*t] + red[4*t+1] + red[4*t+2] + red[4*t+3] + b_nw[0];
        float dv = 1.f / (1.f + __expf(-s));
        dw_l[t] = dv;
        aw_out[(size_t)b * 2 * NN + nb + t] = dv;
    }
    __syncthreads();

    #pragma unroll
    for (int mt = 0; mt < 2; ++mt) {
        #pragma unroll
        for (int nt = 0; nt < 4; ++nt) {
            const int e = wn*64 + nt*16 + l16;
            const float bsv = b_self[e];
            #pragma unroll
            for (int r = 0; r < 4; ++r) {
                const int nl = wm*32 + mt*16 + quad*4 + r;
                const size_t idx = (size_t)(n0 + nl) * DD + e;
                si_out[idx] = accs[mt][nt][r] + bsv;
                const float yv = dw_l[nl] * accp[mt][nt][r];
                const unsigned short ub = f2bf(yv);
                yne_out[idx] = ub;
                ytl[e*72 + nl] = ub;
            }
        }
    }
    __syncthreads();
    {
        const int e = t >> 1, half = t & 1;
        const i32x4* src = (const i32x4*)&ytl[e*72 + half*32];
        i32x4 v0 = src[0], v1 = src[1], v2 = src[2], v3 = src[3];
        i32x4* dst = (i32x4*)(yT_out + (size_t)(b*DD + e) * NN + nb + half*32);
        dst[0] = v0; dst[1] = v1; dst[2] = v2; dst[3] = v3;
    }
}

// kernB0: step-0 B, x = node, self-contained f32 weight conversion (R0-proven).
__global__ __launch_bounds__(256) void kernB0(
    const float* __restrict__ node,
    const float* __restrict__ w_nw, const float* __restrict__ b_nw,
    const float* __restrict__ w_self, const float* __restrict__ b_self,
    const float* __restrict__ w_punct,
    float* __restrict__ si, unsigned short* __restrict__ yne,
    unsigned short* __restrict__ yT, float* __restrict__ aw)
{
    kernB_body<false>(blockIdx.x * 64, node, w_nw, b_nw, w_self, b_self, w_punct,
                      si, yne, yT, aw);
}

// kernB1: step-1 B with preconverted bf16 weights.
__global__ __launch_bounds__(256) void kernB1(
    const float* __restrict__ x,
    const unsigned short* __restrict__ wsb, const unsigned short* __restrict__ wpb,
    const float* __restrict__ w_nw, const float* __restrict__ b_nw,
    const float* __restrict__ b_self,
    float* __restrict__ si, unsigned short* __restrict__ yne,
    unsigned short* __restrict__ yT, float* __restrict__ aw1)
{
    kernB_body<true>(blockIdx.x * 64, x, w_nw, b_nw, wsb, b_self, wpb,
                     si, yne, yT, aw1);
}

// ---------------------------------------------------------------------------
// kernC (R0-proven structure): agg = Ptilde @ yhat, Ptilde from packed bits
// (LDS-resident), B-fragments direct from yT. ZERO barriers in the K-loop.
// XCD-aware mapping b = blockIdx&7 (bijective, 256%8==0) -> the 32 blocks
// sharing batch-b's 512KB yT panel land on one XCD (L2 reuse).
// Epilogue: x = relu(si + scale*(acc - pdm*yhat_i)).
// ---------------------------------------------------------------------------
__global__ __launch_bounds__(256) void kernC(
    const unsigned* __restrict__ pk,        // [B*N][64] packed bits
    const float* __restrict__ scale_g, const float* __restrict__ pdm_g,
    const unsigned short* __restrict__ yT,  // [B][D][N] bf16
    const float* __restrict__ si,           // [B*N][D]
    const unsigned short* __restrict__ yne, // [B*N][D] bf16
    float* __restrict__ x_out)              // [B*N][D]
{
    __shared__ unsigned pPk[64 * 68];       // 64 rows x 64 words, pad 68
    __shared__ float scale_l[64];
    __shared__ float pdm_l[64];

    const int t  = threadIdx.x;
    const int b  = blockIdx.x & 7;          // XCD-aware batch mapping
    const int i0 = (blockIdx.x >> 3) * 64;
    const size_t rg0 = (size_t)b * NN + i0;

    #pragma unroll
    for (int r = 0; r < 4; ++r) {
        const int u   = r * 256 + t;
        const int row = u >> 4;
        const int wq  = (u & 15) * 4;
        i32x4 v = *(const i32x4*)(pk + (rg0 + row) * 64 + wq);
        *(i32x4*)&pPk[row * 68 + wq] = v;
    }
    if (t < 64) {
        scale_l[t] = scale_g[rg0 + t];
        pdm_l[t]   = pdm_g[rg0 + t];
    }
    __syncthreads();

    const int wn = t >> 6, lane = t & 63;
    const int quad = lane >> 4, l16 = lane & 15;
    const unsigned short* yTb = yT + (size_t)b * DD * NN;

    f32x4 acc[4][2] = {};

    #pragma unroll 4
    for (int kk = 0; kk < 64; ++kk) {
        bf16x8 bfr[2];
        #pragma unroll
        for (int nt = 0; nt < 2; ++nt) {
            const int e = wn*32 + nt*16 + l16;
            bfr[nt] = *(const bf16x8*)(yTb + (size_t)e * NN + kk*32 + quad*8);
        }
        bf16x8 af[4];
        #pragma unroll
        for (int mt = 0; mt < 4; ++mt) {
            const unsigned w = pPk[(mt*16 + l16) * 68 + kk];
            const unsigned by = (w >> (quad * 8)) & 0xFFu;
            i32x4 ex;
            ex.x = ((by &   1u) ? 0x3F80 : 0) | ((by &   2u) ? 0x3F800000 : 0);
            ex.y = ((by &   4u) ? 0x3F80 : 0) | ((by &   8u) ? 0x3F800000 : 0);
            ex.z = ((by &  16u) ? 0x3F80 : 0) | ((by &  32u) ? 0x3F800000 : 0);
            ex.w = ((by &  64u) ? 0x3F80 : 0) | ((by & 128u) ? 0x3F800000 : 0);
            union { i32x4 i; bf16x8 h; } cv; cv.i = ex;
            af[mt] = cv.h;
        }
        #pragma unroll
        for (int mt = 0; mt < 4; ++mt)
            #pragma unroll
            for (int nt = 0; nt < 2; ++nt)
                acc[mt][nt] = __builtin_amdgcn_mfma_f32_16x16x32_bf16(af[mt], bfr[nt], acc[mt][nt], 0, 0, 0);
    }

    #pragma unroll
    for (int mt = 0; mt < 4; ++mt) {
        #pragma unroll
        for (int nt = 0; nt < 2; ++nt) {
            const int e = wn*32 + nt*16 + l16;
            #pragma unroll
            for (int r = 0; r < 4; ++r) {
                const int row = mt*16 + quad*4 + r;
                const size_t idx = (rg0 + row) * DD + e;
                const float yv = bf2f(yne[idx]);
                float v = si[idx] + scale_l[row] * (acc[mt][nt][r] - pdm_l[row] * yv);
                x_out[idx] = fmaxf(v, 0.f);
            }
        }
    }
}

extern "C" void kernel_launch(void* const* d_in, const int* in_sizes, int n_in,
                              void* d_out, int out_size, void* d_ws, size_t ws_size,
                              hipStream_t stream) {
    const float* node   = (const float*)d_in[0];
    const int*   mask   = (const int*)  d_in[1];
    const int*   punct  = (const int*)  d_in[2];
    const float* w_nw   = (const float*)d_in[3];
    const float* b_nw   = (const float*)d_in[4];
    const float* w_self = (const float*)d_in[5];
    const float* b_self = (const float*)d_in[6];
    const float* w_punct= (const float*)d_in[7];

    float* xout = (float*)d_out;
    float* aw   = xout + (size_t)BB * NN * DD;

    char* w = (char*)d_ws;
    float*          si   = (float*)w;                               // 8 MB
    unsigned short* yne  = (unsigned short*)(w + (8u  << 20));      // 4 MB
    unsigned short* yT   = (unsigned short*)(w + (12u << 20));      // 4 MB
    unsigned*       pk   = (unsigned*)(w + (16u << 20));            // 4 MB
    float*          scl  = (float*)(w + (20u << 20));               // 64 KB
    float*          pdm  = (float*)(w + (20u << 20) + (64u << 10)); // 64 KB
    unsigned short* wsb  = (unsigned short*)(w + (21u << 20));      // 32 KB
    unsigned short* wpb  = (unsigned short*)(w + (21u << 20) + (32u << 10)); // 32 KB

    dim3 blk(256);
    kernP2<<<dim3(2064), blk, 0, stream>>>(punct, mask, w_self, w_punct,
                                           pk, scl, pdm, wsb, wpb);
    kernB0<<<dim3(256), blk, 0, stream>>>(node, w_nw, b_nw, w_self, b_self,
                                          w_punct, si, yne, yT, aw);
    kernC<<<dim3(256), blk, 0, stream>>>(pk, scl, pdm, yT, si, yne, xout);
    kernB1<<<dim3(256), blk, 0, stream>>>(xout, wsb, wpb, w_nw, b_nw, b_self,
                                          si, yne, yT, aw + NN);
    kernC<<<dim3(256), blk, 0, stream>>>(pk, scl, pdm, yT, si, yne, xout);
}